// Round 2
// baseline (482.123 us; speedup 1.0000x reference)
//
#include <hip/hip_runtime.h>
#include <cstddef>

constexpr int N0 = 16384, N1 = 4096, N2 = 1024, N3 = 256;
constexpr int E0 = 6 * N0, E1 = 6 * N1, E2 = 6 * N2, E3 = 6 * N3;
constexpr int LOCN = 32 * N0; // 524288

// ---- workspace layout (4-byte units) ----
constexpr size_t OFF_XLZ  = 0;        // 128
constexpr size_t OFF_STAT = 128;      // 384 (6 slots x 64: sum|sumsq)
constexpr size_t OFF_XW   = 512;      // 32768 max (1024x32)
constexpr size_t OFF_YG3  = 33280;    // 16384*3
constexpr size_t OFF_DEG  = 82432;    // 21760 ints (16384+4096+1024+256)
constexpr size_t OFF_RP   = 104192;   // 21764 ints (rowptr, n+1 per graph)
constexpr size_t OFF_CUR  = 125956;   // 21764 ints
constexpr size_t OFF_EIDX = 147720;   // 130560 ints
constexpr size_t OFF_X    = 278528;   // 16384*32
constexpr size_t OFF_Y    = 802816;   // 16384*32

// per-graph offsets (graph 0 = A0/N0, ... graph 3 = A3/N3)
__device__ __constant__ int c_ns[4]  = {N0, N1, N2, N3};
__device__ __constant__ int c_db[4]  = {0, 16384, 20480, 21504};       // deg
__device__ __constant__ int c_rb[4]  = {0, 16385, 20482, 21507};       // rowptr
__device__ __constant__ int c_eb[4]  = {0, 98304, 122880, 129024};     // eidx

// x = z@lin_w + lin_b; xlz = x[32:160]; xw0 = broadcast64(x[:32]@Wg0).
// Also zeroes BN stats and all degree counters.
__global__ void k_lin(const float* __restrict__ z, const float* __restrict__ lin_w,
                      const float* __restrict__ lin_b, const float* __restrict__ Wg0,
                      float* __restrict__ xlz, float* __restrict__ xw0,
                      float* __restrict__ stats, int* __restrict__ deg) {
    __shared__ float zl[128];
    __shared__ float xl[160];
    __shared__ float xwl[32];
    int t = threadIdx.x;
    for (int i = t; i < 384; i += 256) stats[i] = 0.f;
    for (int i = t; i < 21760; i += 256) deg[i] = 0;
    if (t < 128) zl[t] = z[t];
    __syncthreads();
    if (t < 160) {
        float s = lin_b[t];
        for (int k = 0; k < 128; k++) s += zl[k] * lin_w[k * 160 + t];
        xl[t] = s;
    }
    __syncthreads();
    if (t < 128) xlz[t] = xl[32 + t];
    if (t < 32) {
        float s = 0.f;
        for (int k = 0; k < 32; k++) s += xl[k] * Wg0[k * 32 + t];
        xwl[t] = s;
    }
    __syncthreads();
    for (int i = t; i < 64 * 32; i += 256) xw0[i] = xwl[i & 31];
}

// in-degree histogram over all 4 graphs
__global__ void k_deg4(const int* __restrict__ A0p, const int* __restrict__ A1p,
                       const int* __restrict__ A2p, const int* __restrict__ A3p,
                       int* __restrict__ deg) {
    int e = blockIdx.x * 256 + threadIdx.x;
    const int* A; int E, dofs;
    if (e < E0)                 { A = A0p; E = E0; dofs = c_db[0]; }
    else if ((e -= E0) < E1)    { A = A1p; E = E1; dofs = c_db[1]; }
    else if ((e -= E1) < E2)    { A = A2p; E = E2; dofs = c_db[2]; }
    else if ((e -= E2) < E3)    { A = A3p; E = E3; dofs = c_db[3]; }
    else return;
    atomicAdd(deg + dofs + A[E + e], 1);
}

// exclusive scan -> rowptr (and copy to cur). One block per graph.
__global__ void __launch_bounds__(1024) k_scan4(const int* __restrict__ deg,
                                                int* __restrict__ rowptr,
                                                int* __restrict__ cur) {
    __shared__ int part[1024];
    int g = blockIdx.x, t = threadIdx.x;
    int n = c_ns[g];
    const int* d = deg + c_db[g];
    int* rp = rowptr + c_rb[g];
    int* cu = cur + c_rb[g];
    int per = (n + 1023) >> 10;
    int base = t * per;
    int loc[16];
    int s = 0;
    for (int i = 0; i < per; i++) {
        int idx = base + i;
        int v = (idx < n) ? d[idx] : 0;
        loc[i] = s; s += v;
    }
    part[t] = s;
    __syncthreads();
    for (int off = 1; off < 1024; off <<= 1) {
        int v = (t >= off) ? part[t - off] : 0;
        __syncthreads();
        part[t] += v;
        __syncthreads();
    }
    int excl = (t > 0) ? part[t - 1] : 0;
    for (int i = 0; i < per; i++) {
        int idx = base + i;
        if (idx < n) { rp[idx] = excl + loc[i]; cu[idx] = excl + loc[i]; }
    }
    if (t == 1023) rp[n] = part[1023];
}

// fill CSR edge-source lists
__global__ void k_fill4(const int* __restrict__ A0p, const int* __restrict__ A1p,
                        const int* __restrict__ A2p, const int* __restrict__ A3p,
                        int* __restrict__ cur, int* __restrict__ eidx) {
    int e = blockIdx.x * 256 + threadIdx.x;
    const int* A; int E, cofs, eofs;
    if (e < E0)                 { A = A0p; E = E0; cofs = c_rb[0]; eofs = c_eb[0]; }
    else if ((e -= E0) < E1)    { A = A1p; E = E1; cofs = c_rb[1]; eofs = c_eb[1]; }
    else if ((e -= E1) < E2)    { A = A2p; E = E2; cofs = c_rb[2]; eofs = c_eb[2]; }
    else if ((e -= E2) < E3)    { A = A3p; E = E3; cofs = c_rb[3]; eofs = c_eb[3]; }
    else return;
    int srcn = A[e], d = A[E + e];
    int slot = atomicAdd(cur + cofs + d, 1);
    eidx[eofs + slot] = srcn;
}

// y = U(n x m) @ xw(m x 32); 32 rows/block, K staged in LDS chunks of 64.
__global__ void k_gemmU32(const float* __restrict__ U, const float* __restrict__ xw, int m,
                          float* __restrict__ y) {
    __shared__ float ut[32 * 64];
    __shared__ float xt[64 * 32];
    int t = threadIdx.x;
    int r0 = blockIdx.x * 32;
    int f = t & 31, rg = t >> 5;
    float a0 = 0, a1 = 0, a2 = 0, a3 = 0;
    for (int k0 = 0; k0 < m; k0 += 64) {
        {
            int row = t >> 3, c0 = (t & 7) * 8;
            const float* src = U + (size_t)(r0 + row) * m + k0 + c0;
            float4 u1 = *(const float4*)src, u2 = *(const float4*)(src + 4);
            float* d = ut + row * 64 + c0;
            *(float4*)d = u1; *(float4*)(d + 4) = u2;
        }
        {
            const float* src = xw + (size_t)k0 * 32 + t * 8;
            float4 u1 = *(const float4*)src, u2 = *(const float4*)(src + 4);
            float* d = xt + t * 8;
            *(float4*)d = u1; *(float4*)(d + 4) = u2;
        }
        __syncthreads();
#pragma unroll
        for (int kk = 0; kk < 64; kk++) {
            float xv = xt[kk * 32 + f];
            a0 += ut[(rg     ) * 64 + kk] * xv;
            a1 += ut[(rg +  8) * 64 + kk] * xv;
            a2 += ut[(rg + 16) * 64 + kk] * xv;
            a3 += ut[(rg + 24) * 64 + kk] * xv;
        }
        __syncthreads();
    }
    int b = (r0 + rg) * 32 + f;
    y[b] = a0;
    y[b + 8 * 32]  = a1;
    y[b + 16 * 32] = a2;
    y[b + 24 * 32] = a3;
}

// yg3 = U0(16384x4096) @ xw3(4096x3); wave-per-row, swizzled LDS operand.
__global__ void k_gemmU3(const float* __restrict__ U0, const float* __restrict__ xw3,
                         float* __restrict__ y) {
    __shared__ float pl[3 * 4096];
    int t = threadIdx.x;
    for (int i = t; i < 12288; i += 256) {
        int k = i / 3, h = i - 3 * k;
        pl[h * 4096 + ((k & 3) << 10) + (k >> 2)] = xw3[i];
    }
    __syncthreads();
    int w = t >> 6, lane = t & 63;
    for (int rr = 0; rr < 4; rr++) {
        int row = blockIdx.x * 16 + w * 4 + rr;
        const float4* up = (const float4*)(U0 + (size_t)row * 4096);
        float a0 = 0, a1 = 0, a2 = 0;
#pragma unroll 4
        for (int c = 0; c < 16; c++) {
            float4 u = up[c * 64 + lane];
            int b = c * 64 + lane;
            a0 += u.x * pl[b]        + u.y * pl[1024 + b]  + u.z * pl[2048 + b]  + u.w * pl[3072 + b];
            a1 += u.x * pl[4096 + b] + u.y * pl[5120 + b]  + u.z * pl[6144 + b]  + u.w * pl[7168 + b];
            a2 += u.x * pl[8192 + b] + u.y * pl[9216 + b]  + u.z * pl[10240 + b] + u.w * pl[11264 + b];
        }
        for (int o = 32; o; o >>= 1) {
            a0 += __shfl_down(a0, o, 64);
            a1 += __shfl_down(a1, o, 64);
            a2 += __shfl_down(a2, o, 64);
        }
        if (lane == 0) {
            y[row * 3] = a0; y[row * 3 + 1] = a1; y[row * 3 + 2] = a2;
        }
    }
}

// Pull-based feast (F=32) fused with finalize + BN stat reduction.
// x[node] = (y[node] + sum_in y[src]) / (deg+1) + bias; stats += (sum, sumsq)
__global__ void k_gather_bn(const int* __restrict__ rowptr, const int* __restrict__ eidx,
                            const float* __restrict__ y, const float* __restrict__ bias,
                            int n, float* __restrict__ xout, float* __restrict__ stats) {
    __shared__ float red[256], red2[256];
    int t = threadIdx.x, f = t & 31, g = t >> 5;
    int node = blockIdx.x * 8 + g;
    float s = 0.f, ss = 0.f;
    if (node < n) {
        int r0 = rowptr[node], r1 = rowptr[node + 1];
        float a = y[(size_t)node * 32 + f];
        for (int r = r0; r < r1; r++) a += y[(size_t)eidx[r] * 32 + f];
        float v = a / (float)(r1 - r0 + 1) + bias[f];
        xout[(size_t)node * 32 + f] = v;
        s = v; ss = v * v;
    }
    red[t] = s; red2[t] = ss;
    __syncthreads();
    if (t < 32) {
        float a = 0.f, b = 0.f;
        for (int j = 0; j < 8; j++) { a += red[t + 32 * j]; b += red2[t + 32 * j]; }
        atomicAdd(stats + t, a);
        atomicAdd(stats + 32 + t, b);
    }
}

// per-node BN + leakyReLU + row @ W(32 x FO) -> y
template <int FO>
__global__ void __launch_bounds__(64) k_bnxw(const float* __restrict__ xin,
                                             const float* __restrict__ stats,
                                             const float* __restrict__ gam,
                                             const float* __restrict__ bet,
                                             const float* __restrict__ W,
                                             float invn, float* __restrict__ out_y) {
    __shared__ float Wl[32 * FO];
    __shared__ float sc[32], sh[32];
    int t = threadIdx.x;
    for (int i = t; i < 32 * FO; i += 64) Wl[i] = W[i];
    if (t < 32) {
        float mu  = stats[t] * invn;
        float var = stats[32 + t] * invn - mu * mu;
        float rs  = rsqrtf(var + 1e-5f);
        float scv = rs * gam[t];
        sc[t] = scv; sh[t] = bet[t] - mu * scv;
    }
    __syncthreads();
    int node = blockIdx.x * 64 + t;
    float x[32];
    const float4* xp = (const float4*)(xin + (size_t)node * 32);
#pragma unroll
    for (int j = 0; j < 8; j++) {
        float4 v = xp[j];
        x[4 * j] = v.x; x[4 * j + 1] = v.y; x[4 * j + 2] = v.z; x[4 * j + 3] = v.w;
    }
#pragma unroll
    for (int k = 0; k < 32; k++) {
        float v = sc[k] * x[k] + sh[k];
        x[k] = v > 0.f ? v : 0.01f * v;
    }
    float yv[FO];
#pragma unroll
    for (int q = 0; q < FO; q++) {
        float s = 0.f;
#pragma unroll
        for (int k = 0; k < 32; k++) s += x[k] * Wl[k * FO + q];
        yv[q] = s;
    }
    float* yp = out_y + (size_t)node * FO;
#pragma unroll
    for (int q = 0; q < FO; q++) yp[q] = yv[q];
}

// fused: y0l = (xlz @ loc_w + loc_b) @ Wl0, 32 nodes per block
__global__ void k_matvec_y(const float* __restrict__ xlz, const float* __restrict__ loc_w,
                           const float* __restrict__ loc_b, const float* __restrict__ W,
                           float* __restrict__ out_y) {
    __shared__ float xs[128];
    __shared__ float xrow[1024];
    __shared__ float Wl[1024];
    int t = threadIdx.x;
    if (t < 128) xs[t] = xlz[t];
    for (int i = t; i < 1024; i += 256) Wl[i] = W[i];
    __syncthreads();
    size_t j0 = (size_t)blockIdx.x * 1024 + t * 4;
    float4 acc = *(const float4*)(loc_b + j0);
#pragma unroll 4
    for (int k = 0; k < 128; k++) {
        float xk = xs[k];
        float4 w = *(const float4*)(loc_w + (size_t)k * LOCN + j0);
        acc.x += xk * w.x; acc.y += xk * w.y; acc.z += xk * w.z; acc.w += xk * w.w;
    }
    *(float4*)(xrow + t * 4) = acc;
    __syncthreads();
#pragma unroll
    for (int q = 0; q < 4; q++) {
        int idx = q * 256 + t;
        int nn = idx >> 5, f = idx & 31;
        float s = 0.f;
        const float* xr = xrow + nn * 32;
#pragma unroll
        for (int k = 0; k < 32; k++) s += xr[k] * Wl[k * 32 + f];
        out_y[(size_t)blockIdx.x * 1024 + idx] = s;
    }
}

// final: pull both F=3 feasts over A0 and combine
__global__ void k_final(const int* __restrict__ rowptr, const int* __restrict__ eidx,
                        const float* __restrict__ yg, const float* __restrict__ yl,
                        const float* __restrict__ bg3, const float* __restrict__ bl3,
                        float* __restrict__ out) {
    int t = blockIdx.x * 256 + threadIdx.x;
    int node = t >> 2, r = t & 3;
    if (node >= N0 || r >= 3) return;
    int r0 = rowptr[node], r1 = rowptr[node + 1];
    float ag = yg[node * 3 + r], al = yl[node * 3 + r];
    for (int e = r0; e < r1; e++) {
        int srcn = eidx[e];
        ag += yg[srcn * 3 + r];
        al += yl[srcn * 3 + r];
    }
    float inv = 1.f / (float)(r1 - r0 + 1);
    out[node * 3 + r] = 0.01f * (ag * inv + bg3[r]) + 0.99f * (al * inv + bl3[r]);
}

extern "C" void kernel_launch(void* const* d_in, const int* in_sizes, int n_in,
                              void* d_out, int out_size, void* d_ws, size_t ws_size,
                              hipStream_t stream) {
    const float* z     = (const float*)d_in[0];
    const float* lin_w = (const float*)d_in[1];
    const float* lin_b = (const float*)d_in[2];
    const float* loc_w = (const float*)d_in[3];
    const float* loc_b = (const float*)d_in[4];
    const float* Wg    = (const float*)d_in[5];
    const float* bg    = (const float*)d_in[8];
    const float* Wg3   = (const float*)d_in[9];
    const float* bg3   = (const float*)d_in[12];
    const float* Wl    = (const float*)d_in[13];
    const float* bl    = (const float*)d_in[16];
    const float* Wl3   = (const float*)d_in[17];
    const float* bl3   = (const float*)d_in[20];
    const float* gam_g = (const float*)d_in[21];
    const float* bet_g = (const float*)d_in[22];
    const float* gam_l = (const float*)d_in[23];
    const float* bet_l = (const float*)d_in[24];
    const float* U0    = (const float*)d_in[25];
    const float* U1    = (const float*)d_in[26];
    const float* U2    = (const float*)d_in[27];
    const float* U3    = (const float*)d_in[28];
    const int* A0p = (const int*)d_in[29];
    const int* A1p = (const int*)d_in[30];
    const int* A2p = (const int*)d_in[31];
    const int* A3p = (const int*)d_in[32];

    float* ws    = (float*)d_ws;
    int*   wsi   = (int*)d_ws;
    float* xlz   = ws + OFF_XLZ;
    float* stats = ws + OFF_STAT;
    float* bxw   = ws + OFF_XW;
    float* yg3   = ws + OFF_YG3;
    int*   deg   = wsi + OFF_DEG;
    int*   rp    = wsi + OFF_RP;
    int*   cur   = wsi + OFF_CUR;
    int*   eidx  = wsi + OFF_EIDX;
    float* bx    = ws + OFF_X;
    float* by    = ws + OFF_Y;
    float* out   = (float*)d_out;

    constexpr int ETOT = E0 + E1 + E2 + E3;

    // head + zero stats/deg
    k_lin<<<1, 256, 0, stream>>>(z, lin_w, lin_b, Wg, xlz, bxw, stats, deg);
    // CSR build (all 4 graphs)
    k_deg4<<<(ETOT + 255) / 256, 256, 0, stream>>>(A0p, A1p, A2p, A3p, deg);
    k_scan4<<<4, 1024, 0, stream>>>(deg, rp, cur);
    k_fill4<<<(ETOT + 255) / 256, 256, 0, stream>>>(A0p, A1p, A2p, A3p, cur, eidx);

    // ---- global path ----
    // layer 0: U3 (256x64) over A3
    k_gemmU32<<<N3 / 32, 256, 0, stream>>>(U3, bxw, 64, by);
    k_gather_bn<<<(N3 + 7) / 8, 256, 0, stream>>>(rp + 21507, eidx + 129024, by, bg, N3, bx, stats);
    k_bnxw<32><<<N3 / 64, 64, 0, stream>>>(bx, stats, gam_g, bet_g, Wg + 1024, 1.f / N3, bxw);
    // layer 1: U2 (1024x256) over A2
    k_gemmU32<<<N2 / 32, 256, 0, stream>>>(U2, bxw, 256, by);
    k_gather_bn<<<(N2 + 7) / 8, 256, 0, stream>>>(rp + 20482, eidx + 122880, by, bg + 32, N2, bx, stats + 64);
    k_bnxw<32><<<N2 / 64, 64, 0, stream>>>(bx, stats + 64, gam_g + 32, bet_g + 32, Wg + 2048, 1.f / N2, bxw);
    // layer 2: U1 (4096x1024) over A1
    k_gemmU32<<<N1 / 32, 256, 0, stream>>>(U1, bxw, 1024, by);
    k_gather_bn<<<(N1 + 7) / 8, 256, 0, stream>>>(rp + 16385, eidx + 98304, by, bg + 64, N1, bx, stats + 128);
    k_bnxw<3><<<N1 / 64, 64, 0, stream>>>(bx, stats + 128, gam_g + 64, bet_g + 64, Wg3, 1.f / N1, bxw);
    // layer 3: U0 (16384x4096) -> yg3 (aggregation deferred to k_final)
    k_gemmU3<<<N0 / 16, 256, 0, stream>>>(U0, bxw, yg3);

    // ---- local path ----
    k_matvec_y<<<LOCN / 1024, 256, 0, stream>>>(xlz, loc_w, loc_b, Wl, by);
    k_gather_bn<<<N0 / 8, 256, 0, stream>>>(rp, eidx, by, bl, N0, bx, stats + 192);
    k_bnxw<32><<<N0 / 64, 64, 0, stream>>>(bx, stats + 192, gam_l, bet_l, Wl + 1024, 1.f / N0, by);
    k_gather_bn<<<N0 / 8, 256, 0, stream>>>(rp, eidx, by, bl + 32, N0, bx, stats + 256);
    k_bnxw<32><<<N0 / 64, 64, 0, stream>>>(bx, stats + 256, gam_l + 32, bet_l + 32, Wl + 2048, 1.f / N0, by);
    k_gather_bn<<<N0 / 8, 256, 0, stream>>>(rp, eidx, by, bl + 64, N0, bx, stats + 320);
    k_bnxw<3><<<N0 / 64, 64, 0, stream>>>(bx, stats + 320, gam_l + 64, bet_l + 64, Wl3, 1.f / N0, by);

    // combine both F=3 feasts over A0
    k_final<<<N0 * 4 / 256, 256, 0, stream>>>(rp, eidx, yg3, by, bg3, bl3, out);
}